// Round 1
// baseline (161.666 us; speedup 1.0000x reference)
//
#include <hip/hip_runtime.h>
#include <hip/hip_bf16.h>

// Conv2d 3x3 s1 p1, NCHW: X(32,128,56,56) f32 * W(256,128,3,3) f32 -> out(32,256,56,56) f32
// Strategy: pad+convert X to bf16 [N][IC][58][58] in ws, pack W bf16 tap-major,
// then implicit-GEMM with mfma_f32_16x16x32_bf16. M=256(oc), Npix=100352, K=1152.

#define IC 128
#define OC 256
#define HH 56
#define WW 56
#define NB 32
#define PH 58
#define PW 58
#define PS (PH*PW)        // 3364
#define NPIX (HH*WW)      // 3136
#define GPIX (NB*NPIX)    // 100352
#define KDIM (IC*9)       // 1152

#define BM 128
#define BN 128
#define BK 64
#define LDK 72            // padded LDS row stride (elements); 144B = 36 dwords -> bank-rotating

typedef short  bf16x8 __attribute__((ext_vector_type(8)));
typedef float  f32x4  __attribute__((ext_vector_type(4)));

__device__ __forceinline__ unsigned short f2bf(float f) {
  union { float f; unsigned int u; } c; c.f = f;
  unsigned int u = c.u;
  u += 0x7FFFu + ((u >> 16) & 1u);   // round-to-nearest-even
  return (unsigned short)(u >> 16);
}

// ---- prepass 1: pad + convert X -> Xp bf16 [NB][IC][PH][PW], zero border
__global__ __launch_bounds__(256) void pad_x(const float* __restrict__ X,
                                             unsigned short* __restrict__ Xp, int total) {
  int idx = blockIdx.x * 256 + threadIdx.x;
  if (idx >= total) return;
  int plane = idx / PS;              // n*IC + ic
  int rem   = idx - plane * PS;
  int y = rem / PW, x = rem - y * PW;
  float v = 0.f;
  if (y >= 1 && y <= HH && x >= 1 && x <= WW)
    v = X[(long)plane * NPIX + (y - 1) * WW + (x - 1)];
  Xp[idx] = f2bf(v);
}

// ---- prepass 2: W (OIHW f32) -> Wb bf16 [oc][tap*128+ic]
__global__ __launch_bounds__(256) void pack_w(const float* __restrict__ W,
                                              unsigned short* __restrict__ Wb, int total) {
  int idx = blockIdx.x * 256 + threadIdx.x;
  if (idx >= total) return;
  int oc = idx / KDIM;
  int r  = idx - oc * KDIM;
  int t  = r >> 7;                   // tap
  int ic = r & 127;
  Wb[idx] = f2bf(W[(oc * IC + ic) * 9 + t]);
}

// ---- main: implicit GEMM, 128x128 tile, 4 waves, BK=64 (one tap per chunk pair)
__global__ __launch_bounds__(256) void conv_mfma(
    const unsigned short* __restrict__ Xp,
    const unsigned short* __restrict__ Wb,
    float* __restrict__ out) {
  __shared__ __align__(16) unsigned short Alds[BM * LDK];
  __shared__ __align__(16) unsigned short Blds[BN * LDK];

  const int tid  = threadIdx.x;
  const int lane = tid & 63;
  const int wave = tid >> 6;
  const int wm = wave & 1, wn = wave >> 1;   // 2x2 wave grid, 64x64 each

  const int octile = blockIdx.x & 1;
  const int ptile  = blockIdx.x >> 1;
  const int ocb = octile * BM;
  const int pb  = ptile * BN;

  // staging roles: thread stages pixel column spix (B) / oc row spix (A), k-half shalf
  const int spix  = tid & 127;
  const int shalf = tid >> 7;

  int pg   = pb + spix;
  int sn   = pg / NPIX;
  int srem = pg - sn * NPIX;
  int soh  = srem / WW;
  int sow  = srem - soh * WW;
  const unsigned short* xbase = Xp + (long)sn * IC * PS + soh * PW + sow;  // ic=0, tap(0,0)
  const unsigned short* wbase = Wb + (long)(ocb + spix) * KDIM + shalf * 32;

  const int l15 = lane & 15;
  const int lh  = lane >> 4;
  const int aoff = (wm * 64 + l15) * LDK + lh * 8;
  const int boff = (wn * 64 + l15) * LDK + lh * 8;

  f32x4 acc[4][4];
  #pragma unroll
  for (int i = 0; i < 4; ++i)
    #pragma unroll
    for (int j = 0; j < 4; ++j)
      acc[i][j] = (f32x4){0.f, 0.f, 0.f, 0.f};

  for (int kc = 0; kc < 18; ++kc) {
    const int tap = kc >> 1;
    const int kh  = tap / 3;
    const int kw  = tap - kh * 3;
    const int icb = (kc & 1) * 64;

    __syncthreads();   // previous chunk's reads done before overwrite

    // stage A: Wb row (ocb+spix), k cols [kc*64 + shalf*32, +32)
    {
      const int4* src = reinterpret_cast<const int4*>(wbase + kc * 64);
      int4 w0 = src[0], w1 = src[1], w2 = src[2], w3 = src[3];
      int4* dst = reinterpret_cast<int4*>(&Alds[spix * LDK + shalf * 32]);
      dst[0] = w0; dst[1] = w1; dst[2] = w2; dst[3] = w3;
    }

    // stage B: im2col gather, [pix][k] layout (k contiguous per pixel)
    {
      const unsigned short* src = xbase + (icb + shalf * 32) * PS + kh * PW + kw;
      unsigned short* dB = &Blds[spix * LDK + shalf * 32];
      #pragma unroll
      for (int g = 0; g < 4; ++g) {
        bf16x8 v;
        #pragma unroll
        for (int j = 0; j < 8; ++j)
          ((short*)&v)[j] = (short)src[(g * 8 + j) * PS];
        *reinterpret_cast<bf16x8*>(dB + g * 8) = v;
      }
    }
    __syncthreads();

    #pragma unroll
    for (int k2 = 0; k2 < 2; ++k2) {
      bf16x8 af[4], bfr[4];
      #pragma unroll
      for (int mi = 0; mi < 4; ++mi)
        af[mi] = *reinterpret_cast<const bf16x8*>(&Alds[aoff + mi * 16 * LDK + k2 * 32]);
      #pragma unroll
      for (int ni = 0; ni < 4; ++ni)
        bfr[ni] = *reinterpret_cast<const bf16x8*>(&Blds[boff + ni * 16 * LDK + k2 * 32]);
      #pragma unroll
      for (int mi = 0; mi < 4; ++mi)
        #pragma unroll
        for (int ni = 0; ni < 4; ++ni)
          acc[mi][ni] = __builtin_amdgcn_mfma_f32_16x16x32_bf16(af[mi], bfr[ni], acc[mi][ni], 0, 0, 0);
    }
  }

  // epilogue: D row=(lane>>4)*4+reg (oc), col=lane&15 (pixel)  [m89-verified layout]
  #pragma unroll
  for (int ni = 0; ni < 4; ++ni) {
    int pgl  = pb + wn * 64 + ni * 16 + l15;
    int n    = pgl / NPIX;
    int prow = pgl - n * NPIX;
    #pragma unroll
    for (int mi = 0; mi < 4; ++mi) {
      int oc0 = ocb + wm * 64 + mi * 16 + lh * 4;
      float* op = out + ((long)(n * OC + oc0)) * NPIX + prow;
      #pragma unroll
      for (int r = 0; r < 4; ++r)
        op[(long)r * NPIX] = acc[mi][ni][r];
    }
  }
}

// ---- fallback (only if ws too small): naive direct conv fp32
__global__ __launch_bounds__(256) void conv_naive(const float* __restrict__ X,
                                                  const float* __restrict__ W,
                                                  float* __restrict__ out, int total) {
  int idx = blockIdx.x * 256 + threadIdx.x;
  if (idx >= total) return;
  int prow = idx % NPIX;
  int t    = idx / NPIX;
  int oc   = t % OC;
  int n    = t / OC;
  int oh = prow / WW, ow = prow % WW;
  float s = 0.f;
  for (int ic = 0; ic < IC; ++ic) {
    const float* xp = X + ((long)(n * IC + ic)) * NPIX;
    const float* wp = W + ((long)(oc * IC + ic)) * 9;
    #pragma unroll
    for (int kh = 0; kh < 3; ++kh) {
      int ih = oh + kh - 1;
      if (ih < 0 || ih >= HH) continue;
      #pragma unroll
      for (int kw = 0; kw < 3; ++kw) {
        int iw = ow + kw - 1;
        if (iw < 0 || iw >= WW) continue;
        s += xp[ih * WW + iw] * wp[kh * 3 + kw];
      }
    }
  }
  out[idx] = s;
}

extern "C" void kernel_launch(void* const* d_in, const int* in_sizes, int n_in,
                              void* d_out, int out_size, void* d_ws, size_t ws_size,
                              hipStream_t stream) {
  const float* X = (const float*)d_in[0];
  const float* W = (const float*)d_in[1];
  float* out = (float*)d_out;

  const size_t xp_elems = (size_t)NB * IC * PS;   // 13,778,944
  const size_t wb_elems = (size_t)OC * KDIM;      //    294,912
  const size_t need = (xp_elems + wb_elems) * sizeof(unsigned short);  // ~28.15 MB

  if (ws_size >= need) {
    unsigned short* Xp = (unsigned short*)d_ws;
    unsigned short* Wb = Xp + xp_elems;
    int totX = (int)xp_elems;
    pad_x<<<(totX + 255) / 256, 256, 0, stream>>>(X, Xp, totX);
    int totW = (int)wb_elems;
    pack_w<<<(totW + 255) / 256, 256, 0, stream>>>(W, Wb, totW);
    conv_mfma<<<(GPIX / BN) * (OC / BM), 256, 0, stream>>>(Xp, Wb, out);
  } else {
    int tot = NB * OC * NPIX;
    conv_naive<<<(tot + 255) / 256, 256, 0, stream>>>(X, W, out, tot);
  }
}

// Round 2
// 137.745 us; speedup vs baseline: 1.1737x; 1.1737x over previous
//
#include <hip/hip_runtime.h>
#include <hip/hip_bf16.h>

// Conv2d 3x3 s1 p1, NCHW: X(32,128,56,56) f32 * W(256,128,3,3) f32 -> out(32,256,56,56) f32
// R2: repack X -> NHWC-padded bf16 Xt[n][58][58][128]; W -> bf16 [oc][tap*128+ic].
// Implicit GEMM (M=256 oc, N=100352 pix, K=1152) in the m97 structure:
// 128x128 tile, BK=64, global_load_lds width-16 into linear [128][64] LDS,
// 2-barrier loop, mfma_f32_16x16x32_bf16, layout-agnostic k-slot fragments.

#define IC 128
#define OC 256
#define HH 56
#define WW 56
#define NB 32
#define PH 58
#define PW 58
#define PS (PH*PW)        // 3364
#define NPIX (HH*WW)      // 3136
#define GPIX (NB*NPIX)    // 100352
#define KDIM (IC*9)       // 1152

#define BM 128
#define BN 128

typedef short  bf16x8 __attribute__((ext_vector_type(8)));
typedef float  f32x4  __attribute__((ext_vector_type(4)));
typedef unsigned int u32;

__device__ __forceinline__ unsigned short f2bf(float f) {
  union { float f; unsigned int u; } c; c.f = f;
  unsigned int u = c.u;
  u += 0x7FFFu + ((u >> 16) & 1u);   // round-to-nearest-even
  return (unsigned short)(u >> 16);
}

__device__ __forceinline__ void gload16(const unsigned short* g, unsigned short* l) {
  __builtin_amdgcn_global_load_lds(
      (const __attribute__((address_space(1))) u32*)g,
      (__attribute__((address_space(3))) u32*)l, 16, 0, 0);
}

// ---- prepass 1a: zero the padded border of Xt (only border pixels, ~1.9 MB)
__global__ __launch_bounds__(256) void zero_border(unsigned short* __restrict__ Xt, int total) {
  int idx = blockIdx.x * 256 + threadIdx.x;
  if (idx >= total) return;
  int e  = idx & 127;
  int b  = idx >> 7;
  int n  = b / 228;
  int bp = b - n * 228;
  int y, x;
  if (bp < 58)       { y = 0;  x = bp; }
  else if (bp < 116) { y = 57; x = bp - 58; }
  else {
    int b2 = bp - 116;           // 0..111: rows 1..56, cols {0,57}
    y = 1 + (b2 >> 1);
    x = (b2 & 1) * 57;
  }
  Xt[((long)(n * PH + y) * PW + x) * IC + e] = 0;
}

// ---- prepass 1b: NCHW f32 -> NHWC-padded bf16 transpose (LDS-tiled, both sides coalesced)
// block = 64 consecutive pixels of one image (64 | NPIX), 256 threads.
__global__ __launch_bounds__(256) void pad_x_nhwc(const float* __restrict__ X,
                                                  unsigned short* __restrict__ Xt) {
  __shared__ float tile[128][65];
  const int t   = threadIdx.x;
  const int p0  = blockIdx.x * 64;
  const int n   = p0 / NPIX;
  const int rem = p0 - n * NPIX;

  // load: quarter q reads ic = q + 4i, 64 consecutive pixels -> coalesced 256B
  const int pixl = t & 63;
  const int q    = t >> 6;
  const float* src = X + ((long)n * IC + q) * NPIX + rem + pixl;
  #pragma unroll
  for (int i = 0; i < 32; ++i)
    tile[q + i * 4][pixl] = src[(long)i * 4 * NPIX];
  __syncthreads();

  // store: thread owns (pixel t>>2, ic quarter (t&3)*32); 64B contiguous bf16 out
  const int pix = t >> 2;
  const int icq = (t & 3) * 32;
  int p = rem + pix;
  int y = p / WW, x = p - y * WW;
  unsigned short* dst = Xt + ((long)(n * PH + y + 1) * PW + (x + 1)) * IC + icq;
  #pragma unroll
  for (int g = 0; g < 4; ++g) {
    bf16x8 v;
    #pragma unroll
    for (int j = 0; j < 8; ++j)
      ((unsigned short*)&v)[j] = f2bf(tile[icq + g * 8 + j][pix]);
    *reinterpret_cast<bf16x8*>(dst + g * 8) = v;
  }
}

// ---- prepass 2: W (OIHW f32) -> Wb bf16 [oc][tap*128+ic]
__global__ __launch_bounds__(256) void pack_w(const float* __restrict__ W,
                                              unsigned short* __restrict__ Wb, int total) {
  int idx = blockIdx.x * 256 + threadIdx.x;
  if (idx >= total) return;
  int oc = idx / KDIM;
  int r  = idx - oc * KDIM;
  int t  = r >> 7;                   // tap
  int ic = r & 127;
  Wb[idx] = f2bf(W[(oc * IC + ic) * 9 + t]);
}

// ---- main: implicit GEMM, m97 structure
__global__ __launch_bounds__(256) void conv_mfma(
    const unsigned short* __restrict__ Xt,
    const unsigned short* __restrict__ Wb,
    float* __restrict__ out) {
  __shared__ __align__(16) unsigned short Alds[BM * 64];   // [oc_row][k]  16 KB
  __shared__ __align__(16) unsigned short Blds[BN * 64];   // [pix_row][k] 16 KB

  const int tid  = threadIdx.x;
  const int lane = tid & 63;
  const int wave = tid >> 6;
  const int wm = wave & 1, wn = wave >> 1;   // 2x2 wave grid, 64x64 each

  const int octile = blockIdx.x & 1;
  const int ptile  = blockIdx.x >> 1;
  const int ocb = octile * BM;
  const int pb  = ptile * BN;

  // staging roles (global_load_lds): per call c (0..3), wave stages 8 rows (1 KB).
  // lane -> row (lane>>3) within the 8, 16B slice (lane&7) within the 128B row.
  const int srow  = wave * 8 + (lane >> 3);
  const int skoff = (lane & 7) * 8;          // element offset (8 bf16 = 16B)

  const unsigned short* pixbase[4];
  #pragma unroll
  for (int c = 0; c < 4; ++c) {
    int pg = pb + c * 32 + srow;
    int n  = pg / NPIX;
    int rm = pg - n * NPIX;
    int y = rm / WW, x = rm - y * WW;
    // tap (0,0) address: output (y,x) needs padded rows y..y+2, cols x..x+2
    pixbase[c] = Xt + ((long)(n * PH + y) * PW + x) * IC + skoff;
  }
  const unsigned short* wbase = Wb + (long)(ocb + srow) * KDIM + skoff;

  const int l15 = lane & 15;
  const int lh  = lane >> 4;
  const int aoff = (wm * 64 + l15) * 64 + lh * 8;
  const int boff = (wn * 64 + l15) * 64 + lh * 8;

  f32x4 acc[4][4];
  #pragma unroll
  for (int i = 0; i < 4; ++i)
    #pragma unroll
    for (int j = 0; j < 4; ++j)
      acc[i][j] = (f32x4){0.f, 0.f, 0.f, 0.f};

  for (int kc = 0; kc < 18; ++kc) {
    const int tap = kc >> 1;
    const int kh  = tap / 3;
    const int kw  = tap - kh * 3;
    const int goB = ((kh * PW + kw) << 7) + ((kc & 1) << 6);  // tap offset*IC + icb
    const int goA = kc << 6;

    __syncthreads();   // previous chunk's LDS reads done before overwrite
    #pragma unroll
    for (int c = 0; c < 4; ++c) {
      gload16(pixbase[c] + goB, &Blds[(c * 32 + wave * 8) * 64]);
      gload16(wbase + (long)c * 32 * KDIM + goA, &Alds[(c * 32 + wave * 8) * 64]);
    }
    __syncthreads();   // compiler drains vmcnt(0) before this barrier -> data ready

    #pragma unroll
    for (int k2 = 0; k2 < 2; ++k2) {
      bf16x8 af[4], bfr[4];
      #pragma unroll
      for (int mi = 0; mi < 4; ++mi)
        af[mi] = *reinterpret_cast<const bf16x8*>(&Alds[aoff + mi * 16 * 64 + k2 * 32]);
      #pragma unroll
      for (int ni = 0; ni < 4; ++ni)
        bfr[ni] = *reinterpret_cast<const bf16x8*>(&Blds[boff + ni * 16 * 64 + k2 * 32]);
      #pragma unroll
      for (int mi = 0; mi < 4; ++mi)
        #pragma unroll
        for (int ni = 0; ni < 4; ++ni)
          acc[mi][ni] = __builtin_amdgcn_mfma_f32_16x16x32_bf16(af[mi], bfr[ni], acc[mi][ni], 0, 0, 0);
    }
  }

  // epilogue: D row=(lane>>4)*4+reg (oc), col=lane&15 (pixel)  [m89-verified layout]
  #pragma unroll
  for (int ni = 0; ni < 4; ++ni) {
    int pgl  = pb + wn * 64 + ni * 16 + l15;
    int n    = pgl / NPIX;
    int prow = pgl - n * NPIX;
    #pragma unroll
    for (int mi = 0; mi < 4; ++mi) {
      int oc0 = ocb + wm * 64 + mi * 16 + lh * 4;
      float* op = out + ((long)(n * OC + oc0)) * NPIX + prow;
      #pragma unroll
      for (int r = 0; r < 4; ++r)
        op[(long)r * NPIX] = acc[mi][ni][r];
    }
  }
}

// ---- fallback (only if ws too small): naive direct conv fp32
__global__ __launch_bounds__(256) void conv_naive(const float* __restrict__ X,
                                                  const float* __restrict__ W,
                                                  float* __restrict__ out, int total) {
  int idx = blockIdx.x * 256 + threadIdx.x;
  if (idx >= total) return;
  int prow = idx % NPIX;
  int t    = idx / NPIX;
  int oc   = t % OC;
  int n    = t / OC;
  int oh = prow / WW, ow = prow % WW;
  float s = 0.f;
  for (int ic = 0; ic < IC; ++ic) {
    const float* xp = X + ((long)(n * IC + ic)) * NPIX;
    const float* wp = W + ((long)(oc * IC + ic)) * 9;
    #pragma unroll
    for (int kh = 0; kh < 3; ++kh) {
      int ih = oh + kh - 1;
      if (ih < 0 || ih >= HH) continue;
      #pragma unroll
      for (int kw = 0; kw < 3; ++kw) {
        int iw = ow + kw - 1;
        if (iw < 0 || iw >= WW) continue;
        s += xp[ih * WW + iw] * wp[kh * 3 + kw];
      }
    }
  }
  out[idx] = s;
}

extern "C" void kernel_launch(void* const* d_in, const int* in_sizes, int n_in,
                              void* d_out, int out_size, void* d_ws, size_t ws_size,
                              hipStream_t stream) {
  const float* X = (const float*)d_in[0];
  const float* W = (const float*)d_in[1];
  float* out = (float*)d_out;

  const size_t xt_elems = (size_t)NB * PS * IC;   // 13,778,944
  const size_t wb_elems = (size_t)OC * KDIM;      //    294,912
  const size_t need = (xt_elems + wb_elems) * sizeof(unsigned short);  // ~28.15 MB

  if (ws_size >= need) {
    unsigned short* Xt = (unsigned short*)d_ws;
    unsigned short* Wb = Xt + xt_elems;

    int totB = NB * 228 * IC;                      // border elems
    zero_border<<<(totB + 255) / 256, 256, 0, stream>>>(Xt, totB);
    pad_x_nhwc<<<GPIX / 64, 256, 0, stream>>>(X, Xt);
    int totW = (int)wb_elems;
    pack_w<<<(totW + 255) / 256, 256, 0, stream>>>(W, Wb, totW);
    conv_mfma<<<(GPIX / BN) * (OC / BM), 256, 0, stream>>>(Xt, Wb, out);
  } else {
    int tot = NB * OC * NPIX;
    conv_naive<<<(tot + 255) / 256, 256, 0, stream>>>(X, W, out, tot);
  }
}

// Round 3
// 107.629 us; speedup vs baseline: 1.5021x; 1.2798x over previous
//
#include <hip/hip_runtime.h>
#include <hip/hip_bf16.h>

// Conv2d 3x3 s1 p1, NCHW: X(32,128,56,56) f32 * W(256,128,3,3) f32 -> out(32,256,56,56) f32
// R3: 8-phase counted-vmcnt pipeline (m201 template) on implicit GEMM.
// BM=256(oc) x BN=256(pix), BK=64 (2 k-halves of 32), 512 thr / 8 waves (2Mx4N),
// per-wave 128x64, acc[8][4]. LDS 128KB: A[2buf][2kh][256x32] + B same.
// T2 swizzle: addr ^= ((addr>>8)&15)<<4 (involution; write-side via pre-swizzled
// global source, read-side on ds_read addrs). vmcnt(8) per phase, never 0.

#define IC 128
#define OC 256
#define HH 56
#define WW 56
#define NB 32
#define PH 58
#define PW 58
#define PS (PH*PW)
#define NPIX (HH*WW)      // 3136
#define GPIX (NB*NPIX)    // 100352
#define KDIM (IC*9)       // 1152
#define NKT 18            // K-tiles of 64

#define BN 256

typedef short  bf16x8 __attribute__((ext_vector_type(8)));
typedef float  f32x4  __attribute__((ext_vector_type(4)));
typedef unsigned int u32;

__device__ __forceinline__ unsigned short f2bf(float f) {
  union { float f; unsigned int u; } c; c.f = f;
  unsigned int u = c.u;
  u += 0x7FFFu + ((u >> 16) & 1u);
  return (unsigned short)(u >> 16);
}

__device__ __forceinline__ void gload16(const unsigned short* g, unsigned short* l) {
  __builtin_amdgcn_global_load_lds(
      (const __attribute__((address_space(1))) u32*)g,
      (__attribute__((address_space(3))) u32*)l, 16, 0, 0);
}

__device__ __forceinline__ int swz(int a) { return a ^ (((a >> 8) & 15) << 4); }

// ---- prepass 1a: zero padded border of Xt
__global__ __launch_bounds__(256) void zero_border(unsigned short* __restrict__ Xt, int total) {
  int idx = blockIdx.x * 256 + threadIdx.x;
  if (idx >= total) return;
  int e  = idx & 127;
  int b  = idx >> 7;
  int n  = b / 228;
  int bp = b - n * 228;
  int y, x;
  if (bp < 58)       { y = 0;  x = bp; }
  else if (bp < 116) { y = 57; x = bp - 58; }
  else {
    int b2 = bp - 116;
    y = 1 + (b2 >> 1);
    x = (b2 & 1) * 57;
  }
  Xt[((long)(n * PH + y) * PW + x) * IC + e] = 0;
}

// ---- prepass 1b: NCHW f32 -> NHWC-padded bf16 (LDS-tiled transpose)
__global__ __launch_bounds__(256) void pad_x_nhwc(const float* __restrict__ X,
                                                  unsigned short* __restrict__ Xt) {
  __shared__ float tile[128][65];
  const int t   = threadIdx.x;
  const int p0  = blockIdx.x * 64;
  const int n   = p0 / NPIX;
  const int rem = p0 - n * NPIX;

  const int pixl = t & 63;
  const int q    = t >> 6;
  const float* src = X + ((long)n * IC + q) * NPIX + rem + pixl;
  #pragma unroll
  for (int i = 0; i < 32; ++i)
    tile[q + i * 4][pixl] = src[(long)i * 4 * NPIX];
  __syncthreads();

  const int pix = t >> 2;
  const int icq = (t & 3) * 32;
  int p = rem + pix;
  int y = p / WW, x = p - y * WW;
  unsigned short* dst = Xt + ((long)(n * PH + y + 1) * PW + (x + 1)) * IC + icq;
  #pragma unroll
  for (int g = 0; g < 4; ++g) {
    bf16x8 v;
    #pragma unroll
    for (int j = 0; j < 8; ++j)
      ((unsigned short*)&v)[j] = f2bf(tile[icq + g * 8 + j][pix]);
    *reinterpret_cast<bf16x8*>(dst + g * 8) = v;
  }
}

// ---- prepass 2: W (OIHW f32) -> Wb bf16 [oc][tap*128+ic]
__global__ __launch_bounds__(256) void pack_w(const float* __restrict__ W,
                                              unsigned short* __restrict__ Wb, int total) {
  int idx = blockIdx.x * 256 + threadIdx.x;
  if (idx >= total) return;
  int oc = idx / KDIM;
  int r  = idx - oc * KDIM;
  int t  = r >> 7;
  int ic = r & 127;
  Wb[idx] = f2bf(W[(oc * IC + ic) * 9 + t]);
}

// ---- main: 8-phase pipelined implicit GEMM
__global__ __launch_bounds__(512, 2) void conv_mfma8(
    const unsigned short* __restrict__ Xt,
    const unsigned short* __restrict__ Wb,
    float* __restrict__ out) {
  // LDS map (bytes): A units [0,64K): (buf*32768 + kh*16384); B units [64K,128K)
  __shared__ unsigned short lds[65536];   // 128 KB

  const int tid  = threadIdx.x;
  const int lane = tid & 63;
  const int w    = tid >> 6;
  const int wm   = w >> 2, wn = w & 3;
  const int l15  = lane & 15, lh = lane >> 4;

  // XCD swizzle: 392 = 8*49
  const int bid = blockIdx.x;
  const int pb  = ((bid & 7) * 49 + (bid >> 3)) * BN;

  // ---- staging setup: unit = 256 rows x 32 k (16 KB = 1024 slots of 16B).
  // thread covers slots s = (w*2+c)*64 + lane, c=0,1. Linear content offset
  // x = swz(s*16) -> row = x>>6, k-bytes = x&63. Write linear dest, read swz.
  const unsigned short* srcA[2];
  const unsigned short* srcB[2];
  const int dstOff0 = (w * 2 + 0) * 1024;
  const int dstOff1 = (w * 2 + 1) * 1024;
  #pragma unroll
  for (int c = 0; c < 2; ++c) {
    int s   = (w * 2 + c) * 64 + lane;
    int x   = swz(s * 16);
    int row = x >> 6;
    int ke  = (x & 63) >> 1;
    srcA[c] = Wb + (long)row * KDIM + ke;
    int pg = pb + row;
    int n  = pg / NPIX;
    int rm = pg - n * NPIX;
    int y  = rm / WW, xx = rm - y * WW;
    srcB[c] = Xt + ((long)(n * PH + y) * PW + xx) * IC + ke;
  }

  // ---- fragment read addresses (swizzled, unit-base 0; unit strides >= 2^14
  // so swz(a + ubase) == swz(a) + ubase)
  int aAddr[8], bAddr[4];
  #pragma unroll
  for (int m = 0; m < 8; ++m) {
    int a0 = (wm * 128 + m * 16 + l15) * 64 + lh * 16;
    aAddr[m] = swz(a0);
  }
  #pragma unroll
  for (int n = 0; n < 4; ++n) {
    int b0 = (wn * 64 + n * 16 + l15) * 64 + lh * 16;
    bAddr[n] = swz(b0) + 65536;
  }

  auto stA = [&](int tt, int kh) {
    if (tt >= NKT) return;
    int off = tt * 64 + kh * 32;
    char* ub = (char*)lds + ((tt & 1) * 32768 + kh * 16384);
    gload16(srcA[0] + off, (unsigned short*)(ub + dstOff0));
    gload16(srcA[1] + off, (unsigned short*)(ub + dstOff1));
  };
  auto stB = [&](int tt, int kh) {
    if (tt >= NKT) return;
    int tap = tt >> 1;
    int th = tap / 3, tw = tap - th * 3;
    int off = (th * PW + tw) * IC + (tt & 1) * 64 + kh * 32;
    char* ub = (char*)lds + (65536 + (tt & 1) * 32768 + kh * 16384);
    gload16(srcB[0] + off, (unsigned short*)(ub + dstOff0));
    gload16(srcB[1] + off, (unsigned short*)(ub + dstOff1));
  };

  f32x4 acc[8][4];
  #pragma unroll
  for (int m = 0; m < 8; ++m)
    #pragma unroll
    for (int n = 0; n < 4; ++n)
      acc[m][n] = (f32x4){0.f, 0.f, 0.f, 0.f};
  bf16x8 af[8];

  // ---- prologue: 6 units (12 loads/wave), in retirement order
  stA(0, 0); stB(0, 0); stA(0, 1); stB(0, 1); stA(1, 0); stB(1, 0);

  // ---- 72 phases: per phase {vmcnt(8); barrier; stage 1 unit; ds_read frags; 16 MFMA}
  // Stage map: i=0 -> A[t+1,kh1]; i=1 -> B[t+1,kh1]; i=2 -> A[t+2,kh0]; i=3 -> B[t+2,kh0]
  #pragma unroll 2
  for (int t = 0; t < NKT; ++t) {
    #pragma unroll
    for (int i = 0; i < 4; ++i) {
      asm volatile("s_waitcnt vmcnt(8)" ::: "memory");
      __builtin_amdgcn_s_barrier();
      __builtin_amdgcn_sched_barrier(0);
      const int kh = i >> 1, nh = i & 1;

      if (i == 0)      stA(t + 1, 1);
      else if (i == 1) stB(t + 1, 1);
      else if (i == 2) stA(t + 2, 0);
      else             stB(t + 2, 0);

      const char* base = (const char*)lds;
      const int ub = (t & 1) * 32768 + kh * 16384;
      if (nh == 0) {
        #pragma unroll
        for (int m = 0; m < 8; ++m)
          af[m] = *(const bf16x8*)(base + (aAddr[m] + ub));
      }
      bf16x8 b0 = *(const bf16x8*)(base + (bAddr[nh * 2 + 0] + ub));
      bf16x8 b1 = *(const bf16x8*)(base + (bAddr[nh * 2 + 1] + ub));

      __builtin_amdgcn_s_setprio(1);
      #pragma unroll
      for (int m = 0; m < 8; ++m) {
        acc[m][nh * 2 + 0] = __builtin_amdgcn_mfma_f32_16x16x32_bf16(af[m], b0, acc[m][nh * 2 + 0], 0, 0, 0);
        acc[m][nh * 2 + 1] = __builtin_amdgcn_mfma_f32_16x16x32_bf16(af[m], b1, acc[m][nh * 2 + 1], 0, 0, 0);
      }
      __builtin_amdgcn_s_setprio(0);
    }
  }

  // ---- epilogue: D row=(lane>>4)*4+reg (oc), col=lane&15 (pixel)
  #pragma unroll
  for (int ni = 0; ni < 4; ++ni) {
    int pgl  = pb + wn * 64 + ni * 16 + l15;
    int n    = pgl / NPIX;
    int prow = pgl - n * NPIX;
    #pragma unroll
    for (int mi = 0; mi < 8; ++mi) {
      int oc0 = wm * 128 + mi * 16 + lh * 4;
      float* op = out + ((long)(n * OC + oc0)) * NPIX + prow;
      #pragma unroll
      for (int r = 0; r < 4; ++r)
        op[(long)r * NPIX] = acc[mi][ni][r];
    }
  }
}

// ---- fallback: naive direct conv fp32
__global__ __launch_bounds__(256) void conv_naive(const float* __restrict__ X,
                                                  const float* __restrict__ W,
                                                  float* __restrict__ out, int total) {
  int idx = blockIdx.x * 256 + threadIdx.x;
  if (idx >= total) return;
  int prow = idx % NPIX;
  int t    = idx / NPIX;
  int oc   = t % OC;
  int n    = t / OC;
  int oh = prow / WW, ow = prow % WW;
  float s = 0.f;
  for (int ic = 0; ic < IC; ++ic) {
    const float* xp = X + ((long)(n * IC + ic)) * NPIX;
    const float* wp = W + ((long)(oc * IC + ic)) * 9;
    #pragma unroll
    for (int kh = 0; kh < 3; ++kh) {
      int ih = oh + kh - 1;
      if (ih < 0 || ih >= HH) continue;
      #pragma unroll
      for (int kw = 0; kw < 3; ++kw) {
        int iw = ow + kw - 1;
        if (iw < 0 || iw >= WW) continue;
        s += xp[ih * WW + iw] * wp[kh * 3 + kw];
      }
    }
  }
  out[idx] = s;
}

extern "C" void kernel_launch(void* const* d_in, const int* in_sizes, int n_in,
                              void* d_out, int out_size, void* d_ws, size_t ws_size,
                              hipStream_t stream) {
  const float* X = (const float*)d_in[0];
  const float* W = (const float*)d_in[1];
  float* out = (float*)d_out;

  const size_t xt_elems = (size_t)NB * PS * IC;
  const size_t wb_elems = (size_t)OC * KDIM;
  const size_t need = (xt_elems + wb_elems) * sizeof(unsigned short);

  if (ws_size >= need) {
    unsigned short* Xt = (unsigned short*)d_ws;
    unsigned short* Wb = Xt + xt_elems;

    int totB = NB * 228 * IC;
    zero_border<<<(totB + 255) / 256, 256, 0, stream>>>(Xt, totB);
    pad_x_nhwc<<<GPIX / 64, 256, 0, stream>>>(X, Xt);
    int totW = (int)wb_elems;
    pack_w<<<(totW + 255) / 256, 256, 0, stream>>>(W, Wb, totW);
    conv_mfma8<<<GPIX / BN, 512, 0, stream>>>(Xt, Wb, out);
  } else {
    int tot = NB * OC * NPIX;
    conv_naive<<<(tot + 255) / 256, 256, 0, stream>>>(X, W, out, tot);
  }
}

// Round 5
// 97.216 us; speedup vs baseline: 1.6630x; 1.1071x over previous
//
#include <hip/hip_runtime.h>
#include <hip/hip_bf16.h>

// Conv2d 3x3 s1 p1, NCHW: X(32,128,56,56) f32 * W(256,128,3,3) f32 -> out(32,256,56,56) f32
// R5: halo-window staging, corrected pipeline ordering.
// Block = 128oc x 448pix (8 full rows of 56). Per 32-ic slice, stage padded window
// [10][64][32ic] ONCE (serves all 9 taps). A (weights) staged per-tap, TRIPLE buffered.
// Phase = { stage(next); vmcnt(K); s_barrier; sched_barrier; ds_read; MFMA }.
// vmcnt BEFORE barrier => barrier certifies all waves' staged units retired (per-wave
// vmcnt + barrier = global RAW safety). WAR safe: win 2-buf, A 3-buf, skew <= 1 phase.

#define IC 128
#define OC 256
#define HH 56
#define WW 56
#define NB 32
#define PH 58
#define PW 58
#define PS (PH*PW)
#define NPIX (HH*WW)      // 3136
#define GPIX (NB*NPIX)    // 100352
#define KDIM (IC*9)       // 1152

#define BMH 128           // oc per block
#define BNP 448           // pixels per block (8 rows x 56)

// LDS byte map: win buf0 @0 (40960), win buf1 @40960; A bufs @81920 + {0,8192,16384}
#define WINB 40960
#define ABASE 81920

typedef short  bf16x8 __attribute__((ext_vector_type(8)));
typedef float  f32x4  __attribute__((ext_vector_type(4)));
typedef unsigned int u32;

__device__ __forceinline__ unsigned short f2bf(float f) {
  union { float f; unsigned int u; } c; c.f = f;
  unsigned int u = c.u;
  u += 0x7FFFu + ((u >> 16) & 1u);
  return (unsigned short)(u >> 16);
}

__device__ __forceinline__ void gload16(const unsigned short* g, unsigned short* l) {
  __builtin_amdgcn_global_load_lds(
      (const __attribute__((address_space(1))) u32*)g,
      (__attribute__((address_space(3))) u32*)l, 16, 0, 0);
}

// involution on bytes: bits 4-7 ^= bits 8-11 (permutes within 4096B-aligned regions)
__device__ __forceinline__ int swz(int a) { return a ^ (((a >> 8) & 15) << 4); }

// ---- prepass 1a: zero padded border of Xt
__global__ __launch_bounds__(256) void zero_border(unsigned short* __restrict__ Xt, int total) {
  int idx = blockIdx.x * 256 + threadIdx.x;
  if (idx >= total) return;
  int e  = idx & 127;
  int b  = idx >> 7;
  int n  = b / 228;
  int bp = b - n * 228;
  int y, x;
  if (bp < 58)       { y = 0;  x = bp; }
  else if (bp < 116) { y = 57; x = bp - 58; }
  else {
    int b2 = bp - 116;
    y = 1 + (b2 >> 1);
    x = (b2 & 1) * 57;
  }
  Xt[((long)(n * PH + y) * PW + x) * IC + e] = 0;
}

// ---- prepass 1b: NCHW f32 -> NHWC-padded bf16 (LDS-tiled transpose)
__global__ __launch_bounds__(256) void pad_x_nhwc(const float* __restrict__ X,
                                                  unsigned short* __restrict__ Xt) {
  __shared__ float tile[128][65];
  const int t   = threadIdx.x;
  const int p0  = blockIdx.x * 64;
  const int n   = p0 / NPIX;
  const int rem = p0 - n * NPIX;

  const int pixl = t & 63;
  const int q    = t >> 6;
  const float* src = X + ((long)n * IC + q) * NPIX + rem + pixl;
  #pragma unroll
  for (int i = 0; i < 32; ++i)
    tile[q + i * 4][pixl] = src[(long)i * 4 * NPIX];
  __syncthreads();

  const int pix = t >> 2;
  const int icq = (t & 3) * 32;
  int p = rem + pix;
  int y = p / WW, x = p - y * WW;
  unsigned short* dst = Xt + ((long)(n * PH + y + 1) * PW + (x + 1)) * IC + icq;
  #pragma unroll
  for (int g = 0; g < 4; ++g) {
    bf16x8 v;
    #pragma unroll
    for (int j = 0; j < 8; ++j)
      ((unsigned short*)&v)[j] = f2bf(tile[icq + g * 8 + j][pix]);
    *reinterpret_cast<bf16x8*>(dst + g * 8) = v;
  }
}

// ---- prepass 2: W (OIHW f32) -> Wb bf16 [oc][tap*128+ic]
__global__ __launch_bounds__(256) void pack_w(const float* __restrict__ W,
                                              unsigned short* __restrict__ Wb, int total) {
  int idx = blockIdx.x * 256 + threadIdx.x;
  if (idx >= total) return;
  int oc = idx / KDIM;
  int r  = idx - oc * KDIM;
  int t  = r >> 7;
  int ic = r & 127;
  Wb[idx] = f2bf(W[(oc * IC + ic) * 9 + t]);
}

// ---- main: halo-window implicit GEMM
__global__ __launch_bounds__(512) void conv_win(
    const unsigned short* __restrict__ Xt,
    const unsigned short* __restrict__ Wb,
    float* __restrict__ out) {
  __shared__ __align__(16) unsigned short lds[53248];   // 104 KB
  char* const ldsb = (char*)lds;

  const int tid  = threadIdx.x;
  const int lane = tid & 63;
  const int w    = tid >> 6;
  const int wm = w >> 2, wn = w & 3;     // 2M x 4N wave grid; wave tile 64oc x 112pix
  const int l15 = lane & 15, lh = lane >> 4;

  // XCD-aware bijective remap: 448 = 8 x 56
  const int bid   = blockIdx.x;
  const int wg    = (bid & 7) * 56 + (bid >> 3);
  const int ntile = wg >> 1;             // 0..223
  const int mhalf = wg & 1;
  const int n   = ntile / 7;
  const int rg  = ntile - n * 7;
  const int y0  = rg * 8;                // padded top row of window
  const int ocb = mhalf * BMH;

  // ---- A staging source (slot tid: 16B per thread per unit; content pre-swizzled)
  const int xa = swz(tid * 16);
  const unsigned short* srcA = Wb + (long)(ocb + (xa >> 6)) * KDIM + ((xa & 63) >> 1);

  // ---- window staging sources (5 slots/thread; layout [10 rows][64 cols][32ic])
  const unsigned short* srcW[5];
  #pragma unroll
  for (int r = 0; r < 5; ++r) {
    int xw   = swz((tid + r * 512) * 16);
    int slab = xw >> 6;                  // row*64 + col
    int rr   = slab >> 6;
    int cc   = slab & 63; if (cc > 57) cc = 57;     // pad cols 58-63: dup (never read)
    srcW[r] = Xt + ((long)((n * PH + y0 + rr) * PW + cc)) * IC + ((xw & 63) >> 1);
  }

  // ---- fragment linear offsets
  int pixLin[7];
  #pragma unroll
  for (int j = 0; j < 7; ++j) {
    int local = wn * 112 + j * 16 + l15;     // 0..447 within block
    int wy = local / 56, wx = local - wy * 56;
    pixLin[j] = ((wy * 64 + wx) << 6) + lh * 16;
  }
  int aLin[4];
  #pragma unroll
  for (int m = 0; m < 4; ++m)
    aLin[m] = swz(((wm * 64 + m * 16 + l15) << 6) + lh * 16);

  f32x4 acc[4][7];
  #pragma unroll
  for (int m = 0; m < 4; ++m)
    #pragma unroll
    for (int j = 0; j < 7; ++j)
      acc[m][j] = (f32x4){0.f, 0.f, 0.f, 0.f};

  // ---- staging helpers (LDS dest WAVE-UNIFORM; HW scatters lane*16)
  auto stageA = [&](int ab, int icoff) {
    char* d = ldsb + ABASE + ab * 8192 + (tid & ~63) * 16;
    gload16(srcA + icoff, (unsigned short*)d);
  };
  auto stageWin = [&](int icb) {          // slice icb -> buf (icb&1)
    char* base = ldsb + (icb & 1) * WINB + (tid & ~63) * 16;
    #pragma unroll
    for (int r = 0; r < 5; ++r)
      gload16(srcW[r] + icb * 32, (unsigned short*)(base + r * 8192));
  };

  // ---- prologue: window slice 0 (5 loads) + A unit 0 (1 load) => 6 outstanding
  stageWin(0);
  stageA(0, 0);

  // Phase q = icb*9+tap. Read A buf q%3 == tap%3 (9%3==0), win buf icb&1.
  // Stage A[q+1] -> buf (tap+1)%3; at tap==8 also window (icb+1) -> buf (icb+1)&1.
  // vmcnt BEFORE s_barrier: every wave retires the units read this phase.
  for (int icb = 0; icb < 4; ++icb) {
    const int winSel = (icb & 1) * WINB;
    #pragma unroll
    for (int tap = 0; tap < 9; ++tap) {
      if (tap == 8) {
        if (icb < 3) {
          stageWin(icb + 1);
          stageA(0, (icb + 1) * 32);                         // (8+1)%3 == 0
          asm volatile("s_waitcnt vmcnt(6)" ::: "memory");   // retire A[q] only
        } else {
          asm volatile("s_waitcnt vmcnt(0)" ::: "memory");   // final phase
        }
      } else {
        stageA((tap + 1) % 3, icb * 32 + (tap + 1) * 128);
        asm volatile("s_waitcnt vmcnt(1)" ::: "memory");     // retire all but A[q+1]
      }
      __builtin_amdgcn_s_barrier();
      __builtin_amdgcn_sched_barrier(0);

      const int dy = tap / 3, dx = tap - dy * 3;   // compile-time (tap unrolled)
      const int toff = ((dy * 64 + dx) << 6);
      const char* ab = ldsb + ABASE + (tap % 3) * 8192;

      bf16x8 af[4];
      #pragma unroll
      for (int m = 0; m < 4; ++m)
        af[m] = *(const bf16x8*)(ab + aLin[m]);
      bf16x8 bfv[7];
      #pragma unroll
      for (int j = 0; j < 7; ++j) {
        int lin = pixLin[j] + toff;
        bfv[j] = *(const bf16x8*)(ldsb + winSel + swz(lin));
      }

      __builtin_amdgcn_s_setprio(1);
      #pragma unroll
      for (int j = 0; j < 7; ++j)
        #pragma unroll
        for (int m = 0; m < 4; ++m)
          acc[m][j] = __builtin_amdgcn_mfma_f32_16x16x32_bf16(af[m], bfv[j], acc[m][j], 0, 0, 0);
      __builtin_amdgcn_s_setprio(0);
    }
  }

  // ---- epilogue: D row=(lane>>4)*4+reg (oc), col=lane&15 (pixel)
  #pragma unroll
  for (int j = 0; j < 7; ++j) {
    int local = wn * 112 + j * 16 + l15;
    int pidx  = rg * BNP + local;                 // pixel within image
    #pragma unroll
    for (int m = 0; m < 4; ++m) {
      int oc = ocb + wm * 64 + m * 16 + lh * 4;
      float* op = out + ((long)(n * OC + oc)) * NPIX + pidx;
      #pragma unroll
      for (int r = 0; r < 4; ++r)
        op[(long)r * NPIX] = acc[m][j][r];
    }
  }
}

// ---- fallback: naive direct conv fp32
__global__ __launch_bounds__(256) void conv_naive(const float* __restrict__ X,
                                                  const float* __restrict__ W,
                                                  float* __restrict__ out, int total) {
  int idx = blockIdx.x * 256 + threadIdx.x;
  if (idx >= total) return;
  int prow = idx % NPIX;
  int t    = idx / NPIX;
  int oc   = t % OC;
  int n    = t / OC;
  int oh = prow / WW, ow = prow % WW;
  float s = 0.f;
  for (int ic = 0; ic < IC; ++ic) {
    const float* xp = X + ((long)(n * IC + ic)) * NPIX;
    const float* wp = W + ((long)(oc * IC + ic)) * 9;
    #pragma unroll
    for (int kh = 0; kh < 3; ++kh) {
      int ih = oh + kh - 1;
      if (ih < 0 || ih >= HH) continue;
      #pragma unroll
      for (int kw = 0; kw < 3; ++kw) {
        int iw = ow + kw - 1;
        if (iw < 0 || iw >= WW) continue;
        s += xp[ih * WW + iw] * wp[kh * 3 + kw];
      }
    }
  }
  out[idx] = s;
}

extern "C" void kernel_launch(void* const* d_in, const int* in_sizes, int n_in,
                              void* d_out, int out_size, void* d_ws, size_t ws_size,
                              hipStream_t stream) {
  const float* X = (const float*)d_in[0];
  const float* W = (const float*)d_in[1];
  float* out = (float*)d_out;

  const size_t xt_elems = (size_t)NB * PS * IC;
  const size_t wb_elems = (size_t)OC * KDIM;
  const size_t need = (xt_elems + wb_elems) * sizeof(unsigned short);

  if (ws_size >= need) {
    unsigned short* Xt = (unsigned short*)d_ws;
    unsigned short* Wb = Xt + xt_elems;

    int totB = NB * 228 * IC;
    zero_border<<<(totB + 255) / 256, 256, 0, stream>>>(Xt, totB);
    pad_x_nhwc<<<GPIX / 64, 256, 0, stream>>>(X, Xt);
    int totW = (int)wb_elems;
    pack_w<<<(totW + 255) / 256, 256, 0, stream>>>(W, Wb, totW);
    conv_win<<<(GPIX / BNP) * (OC / BMH), 512, 0, stream>>>(Xt, Wb, out);
  } else {
    int tot = NB * OC * NPIX;
    conv_naive<<<(tot + 255) / 256, 256, 0, stream>>>(X, W, out, tot);
  }
}

// Round 7
// 88.780 us; speedup vs baseline: 1.8210x; 1.0950x over previous
//
#include <hip/hip_runtime.h>
#include <hip/hip_bf16.h>

// Conv2d 3x3 s1 p1, NCHW: X(32,128,56,56) f32 * W(256,128,3,3) f32 -> out(32,256,56,56) f32
// R7 = R6 with two fixes:
//  (1) A-register TRIPLE buffer (aReg[3]); tap t reads t%3, prefetch (t+1)%3.
//      R6 bug: tap8's cross-icb prefetch overwrote aReg[0] before tap8's MFMAs read it.
//  (2) sched_barrier(0) after every s_barrier: blocks next-slice ds_reads hoisting
//      between my vmcnt(0) and the barrier (cross-wave RAW race; rule 18).
// Structure: window (input) staged to LDS once per 32-ic slice (double-buffered,
// ONE barrier per slice); weights direct L2->VGPR, prefetched one tap ahead;
// taps = LDS pointer shifts. 8 barriers total. 7 ds_read_b128 per tap.

#define IC 128
#define OC 256
#define HH 56
#define WW 56
#define NB 32
#define PH 58
#define PW 58
#define PS (PH*PW)
#define NPIX (HH*WW)      // 3136
#define GPIX (NB*NPIX)    // 100352
#define KDIM (IC*9)       // 1152

#define BMH 128           // oc per block
#define BNP 448           // pixels per block (8 rows x 56)

#define WINB 40960        // one window buffer: [10 rows][64 cols][32 ic] bf16

typedef short  bf16x8 __attribute__((ext_vector_type(8)));
typedef float  f32x4  __attribute__((ext_vector_type(4)));
typedef unsigned int u32;

__device__ __forceinline__ unsigned short f2bf(float f) {
  union { float f; unsigned int u; } c; c.f = f;
  unsigned int u = c.u;
  u += 0x7FFFu + ((u >> 16) & 1u);
  return (unsigned short)(u >> 16);
}

__device__ __forceinline__ void gload16(const unsigned short* g, unsigned short* l) {
  __builtin_amdgcn_global_load_lds(
      (const __attribute__((address_space(1))) u32*)g,
      (__attribute__((address_space(3))) u32*)l, 16, 0, 0);
}

// involution on bytes: bits 4-7 ^= bits 8-11
__device__ __forceinline__ int swz(int a) { return a ^ (((a >> 8) & 15) << 4); }

// ---- prepass 1a: zero padded border of Xt
__global__ __launch_bounds__(256) void zero_border(unsigned short* __restrict__ Xt, int total) {
  int idx = blockIdx.x * 256 + threadIdx.x;
  if (idx >= total) return;
  int e  = idx & 127;
  int b  = idx >> 7;
  int n  = b / 228;
  int bp = b - n * 228;
  int y, x;
  if (bp < 58)       { y = 0;  x = bp; }
  else if (bp < 116) { y = 57; x = bp - 58; }
  else {
    int b2 = bp - 116;
    y = 1 + (b2 >> 1);
    x = (b2 & 1) * 57;
  }
  Xt[((long)(n * PH + y) * PW + x) * IC + e] = 0;
}

// ---- prepass 1b: NCHW f32 -> NHWC-padded bf16 (LDS-tiled transpose)
__global__ __launch_bounds__(256) void pad_x_nhwc(const float* __restrict__ X,
                                                  unsigned short* __restrict__ Xt) {
  __shared__ float tile[128][65];
  const int t   = threadIdx.x;
  const int p0  = blockIdx.x * 64;
  const int n   = p0 / NPIX;
  const int rem = p0 - n * NPIX;

  const int pixl = t & 63;
  const int q    = t >> 6;
  const float* src = X + ((long)n * IC + q) * NPIX + rem + pixl;
  #pragma unroll
  for (int i = 0; i < 32; ++i)
    tile[q + i * 4][pixl] = src[(long)i * 4 * NPIX];
  __syncthreads();

  const int pix = t >> 2;
  const int icq = (t & 3) * 32;
  int p = rem + pix;
  int y = p / WW, x = p - y * WW;
  unsigned short* dst = Xt + ((long)(n * PH + y + 1) * PW + (x + 1)) * IC + icq;
  #pragma unroll
  for (int g = 0; g < 4; ++g) {
    bf16x8 v;
    #pragma unroll
    for (int j = 0; j < 8; ++j)
      ((unsigned short*)&v)[j] = f2bf(tile[icq + g * 8 + j][pix]);
    *reinterpret_cast<bf16x8*>(dst + g * 8) = v;
  }
}

// ---- prepass 2: W (OIHW f32) -> Wb bf16 [tap][ic_octet s][oc][8 ic]
// idx = ((t*16+s)*256+oc)*8+e ; value = W[oc][s*8+e][t]
__global__ __launch_bounds__(256) void pack_w(const float* __restrict__ W,
                                              unsigned short* __restrict__ Wb, int total) {
  int idx = blockIdx.x * 256 + threadIdx.x;
  if (idx >= total) return;
  int e  = idx & 7;
  int oc = (idx >> 3) & 255;
  int s  = (idx >> 11) & 15;
  int t  = idx >> 15;
  Wb[idx] = f2bf(W[(oc * IC + s * 8 + e) * 9 + t]);
}

// ---- main: halo-window implicit GEMM, barrier-free taps
__global__ __launch_bounds__(512, 2) void conv_win(
    const unsigned short* __restrict__ Xt,
    const unsigned short* __restrict__ Wb,
    float* __restrict__ out) {
  __shared__ __align__(16) unsigned short lds[40960];   // 80 KB: 2 window buffers
  char* const ldsb = (char*)lds;

  const int tid  = threadIdx.x;
  const int lane = tid & 63;
  const int w    = tid >> 6;
  const int wm = w >> 2, wn = w & 3;     // 2M x 4N wave grid; wave tile 64oc x 112pix
  const int l15 = lane & 15, lh = lane >> 4;

  // XCD-aware bijective remap: 448 = 8 x 56
  const int bid   = blockIdx.x;
  const int wg    = (bid & 7) * 56 + (bid >> 3);
  const int ntile = wg >> 1;             // 0..223
  const int mhalf = wg & 1;
  const int n   = ntile / 7;
  const int rg  = ntile - n * 7;
  const int y0  = rg * 8;                // padded top row of window
  const int ocb = mhalf * BMH;

  // ---- A source: per-lane VGPR loads, coalesced (16 lanes x 16B contiguous)
  // elem offset(t, icb, lh, m): (t*16 + icb*4 + lh)*2048 + (ocb+wm*64+m*16+l15)*8
  const unsigned short* aBase = Wb + (size_t)lh * 2048 + (ocb + wm * 64 + l15) * 8;

  // ---- window staging sources (5 slots/thread; layout [10 rows][64 cols][32ic])
  const unsigned short* srcW[5];
  #pragma unroll
  for (int r = 0; r < 5; ++r) {
    int xw   = swz((tid + r * 512) * 16);
    int slab = xw >> 6;                  // row*64 + col
    int rr   = slab >> 6;
    int cc   = slab & 63; if (cc > 57) cc = 57;     // pad cols 58-63: dup (never read)
    srcW[r] = Xt + ((long)((n * PH + y0 + rr) * PW + cc)) * IC + ((xw & 63) >> 1);
  }

  // ---- fragment linear offsets (window)
  int pixLin[7];
  #pragma unroll
  for (int j = 0; j < 7; ++j) {
    int local = wn * 112 + j * 16 + l15;     // 0..447 within block
    int wy = local / 56, wx = local - wy * 56;
    pixLin[j] = ((wy * 64 + wx) << 6) + lh * 16;
  }

  f32x4 acc[4][7];
  #pragma unroll
  for (int m = 0; m < 4; ++m)
    #pragma unroll
    for (int j = 0; j < 7; ++j)
      acc[m][j] = (f32x4){0.f, 0.f, 0.f, 0.f};

  auto stageWin = [&](int icb) {          // slice icb -> buf (icb&1); wave-uniform dest
    char* base = ldsb + (icb & 1) * WINB + (tid & ~63) * 16;
    #pragma unroll
    for (int r = 0; r < 5; ++r)
      gload16(srcW[r] + icb * 32, (unsigned short*)(base + r * 8192));
  };

  // ---- prologue
  stageWin(0);
  bf16x8 aReg[3][4];
  #pragma unroll
  for (int m = 0; m < 4; ++m)
    aReg[0][m] = *(const bf16x8*)(aBase + m * 128);        // A(t=0, icb=0)
  asm volatile("s_waitcnt vmcnt(0)" ::: "memory");
  __builtin_amdgcn_s_barrier();
  __builtin_amdgcn_sched_barrier(0);

  for (int icb = 0; icb < 4; ++icb) {
    if (icb < 3) stageWin(icb + 1);
    const int winSel = (icb & 1) * WINB;
    const size_t aIcb = (size_t)icb * 4 * 2048;

    #pragma unroll
    for (int tap = 0; tap < 9; ++tap) {
      // prefetch next tap's A into slot (tap+1)%3; tap==8 -> slot 0 = next icb's tap0
      if (tap < 8) {
        #pragma unroll
        for (int m = 0; m < 4; ++m)
          aReg[(tap + 1) % 3][m] =
              *(const bf16x8*)(aBase + aIcb + (size_t)(tap + 1) * 16 * 2048 + m * 128);
      } else if (icb < 3) {
        #pragma unroll
        for (int m = 0; m < 4; ++m)
          aReg[0][m] =
              *(const bf16x8*)(aBase + (size_t)(icb + 1) * 4 * 2048 + m * 128);
      }

      const int dy = tap / 3, dx = tap - dy * 3;   // compile-time (tap unrolled)
      const int toff = ((dy * 64 + dx) << 6);

      bf16x8 bfv[7];
      #pragma unroll
      for (int j = 0; j < 7; ++j)
        bfv[j] = *(const bf16x8*)(ldsb + winSel + swz(pixLin[j] + toff));

      __builtin_amdgcn_s_setprio(1);
      #pragma unroll
      for (int j = 0; j < 7; ++j)
        #pragma unroll
        for (int m = 0; m < 4; ++m)
          acc[m][j] = __builtin_amdgcn_mfma_f32_16x16x32_bf16(aReg[tap % 3][m], bfv[j],
                                                              acc[m][j], 0, 0, 0);
      __builtin_amdgcn_s_setprio(0);
    }

    // window(icb+1) fully staged (all waves) before reading it; WAR on buf icb&1
    // certified for the stage at icb+2 by this same barrier.
    asm volatile("s_waitcnt vmcnt(0)" ::: "memory");
    __builtin_amdgcn_s_barrier();
    __builtin_amdgcn_sched_barrier(0);
  }

  // ---- epilogue: D row=(lane>>4)*4+reg (oc), col=lane&15 (pixel)
  #pragma unroll
  for (int j = 0; j < 7; ++j) {
    int local = wn * 112 + j * 16 + l15;
    int pidx  = rg * BNP + local;                 // pixel within image
    #pragma unroll
    for (int m = 0; m < 4; ++m) {
      int oc = ocb + wm * 64 + m * 16 + lh * 4;
      float* op = out + ((long)(n * OC + oc)) * NPIX + pidx;
      #pragma unroll
      for (int r = 0; r < 4; ++r)
        op[(long)r * NPIX] = acc[m][j][r];
    }
  }
}

// ---- fallback: naive direct conv fp32
__global__ __launch_bounds__(256) void conv_naive(const float* __restrict__ X,
                                                  const float* __restrict__ W,
                                                  float* __restrict__ out, int total) {
  int idx = blockIdx.x * 256 + threadIdx.x;
  if (idx >= total) return;
  int prow = idx % NPIX;
  int t    = idx / NPIX;
  int oc   = t % OC;
  int n    = t / OC;
  int oh = prow / WW, ow = prow % WW;
  float s = 0.f;
  for (int ic = 0; ic < IC; ++ic) {
    const float* xp = X + ((long)(n * IC + ic)) * NPIX;
    const float* wp = W + ((long)(oc * IC + ic)) * 9;
    #pragma unroll
    for (int kh = 0; kh < 3; ++kh) {
      int ih = oh + kh - 1;
      if (ih < 0 || ih >= HH) continue;
      #pragma unroll
      for (int kw = 0; kw < 3; ++kw) {
        int iw = ow + kw - 1;
        if (iw < 0 || iw >= WW) continue;
        s += xp[ih * WW + iw] * wp[kh * 3 + kw];
      }
    }
  }
  out[idx] = s;
}

extern "C" void kernel_launch(void* const* d_in, const int* in_sizes, int n_in,
                              void* d_out, int out_size, void* d_ws, size_t ws_size,
                              hipStream_t stream) {
  const float* X = (const float*)d_in[0];
  const float* W = (const float*)d_in[1];
  float* out = (float*)d_out;

  const size_t xt_elems = (size_t)NB * PS * IC;
  const size_t wb_elems = (size_t)9 * 16 * 256 * 8;   // 294,912
  const size_t need = (xt_elems + wb_elems) * sizeof(unsigned short);

  if (ws_size >= need) {
    unsigned short* Xt = (unsigned short*)d_ws;
    unsigned short* Wb = Xt + xt_elems;

    int totB = NB * 228 * IC;
    zero_border<<<(totB + 255) / 256, 256, 0, stream>>>(Xt, totB);
    pad_x_nhwc<<<GPIX / 64, 256, 0, stream>>>(X, Xt);
    int totW = (int)wb_elems;
    pack_w<<<(totW + 255) / 256, 256, 0, stream>>>(W, Wb, totW);
    conv_win<<<(GPIX / BNP) * (OC / BMH), 512, 0, stream>>>(Xt, Wb, out);
  } else {
    int tot = NB * OC * NPIX;
    conv_naive<<<(tot + 255) / 256, 256, 0, stream>>>(X, W, out, tot);
  }
}